// Round 7
// baseline (430.957 us; speedup 1.0000x reference)
//
#include <hip/hip_runtime.h>

// LIF neuron forward scan, x: [B=64, F=2048, T=512] f32 (scan over contiguous T).
//   v = v + (x_t - v) * (DT/TAU);  s = (v >= 1); v *= (1 - s)
//
// Two pure-stream kernels (output is statistically all-zero: threshold is
// 6.2 sigma of the membrane EMA; absmax=0.0 confirmed rounds 1-6):
//   1. zfill     : write-only nontemporal zero-fill of d_out (pure write
//                  stream, same shape as the harness fill that runs 6.4 TB/s).
//   2. lif_scan  : read-only wave-parallel affine scan. Dense f4 loads (lane
//                  l holds t[4l..4l+4) of each 256-element half-row), scan
//                  done DIRECTLY in this layout (no redistribution shfls):
//                  per-lane 4-step fold -> 6-step shfl_up Hillis-Steele with
//                  compile-time multipliers alpha^(4*2^s); half-to-half carry
//                  folded into lane 0's segment. Exact in-lane re-run tracks
//                  max(v); ballot(max>=0.95) == 0 (margin >> 1e-5 scan
//                  rounding) -> row provably spike-free -> nothing to write.
//                  Else (~never) exact serial reference re-scan decides and
//                  scatters 1.0f (ordered after zfill by stream order; rows
//                  uniquely owned -> race-free).
// Rows independent (v0=0/row); 2-deep named-buffer prefetch, static indices.

typedef float f4 __attribute__((ext_vector_type(4)));

#define T_LEN 512
#define RPW 32              // rows per wave
#define WPB 4               // waves per block

__global__ __launch_bounds__(256)
void zfill_kernel(f4* __restrict__ out, int n4) {
    const f4 z = {0.f, 0.f, 0.f, 0.f};
    int i = blockIdx.x * 256 + threadIdx.x;
    const int stride = gridDim.x * 256;
    for (; i < n4; i += stride)
        __builtin_nontemporal_store(z, out + i);
}

__global__ __launch_bounds__(256, 4)
void lif_scan_kernel(const float* __restrict__ x, float* __restrict__ out) {
    constexpr float  K   = 1.0f / 20.0f;
    constexpr double Kd  = (double)(1.0f / 20.0f);
    constexpr double A1d = 1.0 - Kd;
    constexpr double A2d = A1d * A1d;
    constexpr double A4d = A2d * A2d;        // per-lane segment (4 steps)
    constexpr double A8d = A4d * A4d;
    constexpr double A16d = A8d * A8d;
    constexpr double A32d = A16d * A16d;
    constexpr double A64d = A32d * A32d;
    constexpr double A128d = A64d * A64d;
    constexpr float C4[6] = {(float)A4d,  (float)A8d,  (float)A16d,
                             (float)A32d, (float)A64d, (float)A128d};
    constexpr float A4f = (float)A4d;

    const int lane = threadIdx.x & 63;
    const int wid  = blockIdx.x * WPB + (threadIdx.x >> 6);
    const size_t row0 = (size_t)wid * RPW;

    // prologue: rows 0,1 (A = t[0,256), B = t[256,512); dense f4 per lane)
    f4 A0, B0, A1v, B1v;
    {
        const float* p0 = x + row0 * T_LEN + lane * 4;
        A0  = __builtin_nontemporal_load((const f4*)p0);
        B0  = __builtin_nontemporal_load((const f4*)(p0 + 256));
        A1v = __builtin_nontemporal_load((const f4*)(p0 + T_LEN));
        B1v = __builtin_nontemporal_load((const f4*)(p0 + T_LEN + 256));
    }

#define STEP(RR, AV, BV)                                                      \
    {                                                                         \
        const size_t base = (row0 + (RR)) * (size_t)T_LEN;                    \
        const f4 qa = AV, qb = BV;                                            \
        if ((RR) + 2 < RPW) {   /* 2-deep prefetch into this buffer pair */   \
            const float* pr = x + base + 2 * T_LEN + lane * 4;                \
            AV = __builtin_nontemporal_load((const f4*)pr);                   \
            BV = __builtin_nontemporal_load((const f4*)(pr + 256));           \
        }                                                                     \
        /* fold + scan, half A (t < 256) */                                   \
        float bA = 0.0f;                                                      \
        _Pragma("unroll")                                                     \
        for (int j = 0; j < 4; ++j) bA = bA + (qa[j] - bA) * K;               \
        _Pragma("unroll")                                                     \
        for (int s = 0; s < 6; ++s) {                                         \
            const float o = __shfl_up(bA, 1 << s);                            \
            const float f = fmaf(o, C4[s], bA);                               \
            bA = (lane >= (1 << s)) ? f : bA;                                 \
        }                                                                     \
        const float carry = __shfl(bA, 63);   /* v after t[0,256) */          \
        float uA = __shfl_up(bA, 1);                                          \
        uA = (lane == 0) ? 0.0f : uA;                                         \
        /* fold + scan, half B (carry folded into lane 0's segment) */        \
        float bB = 0.0f;                                                      \
        _Pragma("unroll")                                                     \
        for (int j = 0; j < 4; ++j) bB = bB + (qb[j] - bB) * K;               \
        bB = (lane == 0) ? fmaf(carry, A4f, bB) : bB;                         \
        _Pragma("unroll")                                                     \
        for (int s = 0; s < 6; ++s) {                                         \
            const float o = __shfl_up(bB, 1 << s);                            \
            const float f = fmaf(o, C4[s], bB);                               \
            bB = (lane >= (1 << s)) ? f : bB;                                 \
        }                                                                     \
        float uB = __shfl_up(bB, 1);                                          \
        uB = (lane == 0) ? carry : uB;                                        \
        /* exact in-lane recurrence from entry potentials; track max */       \
        float v = uA, mx = -1.0f;                                             \
        _Pragma("unroll")                                                     \
        for (int j = 0; j < 4; ++j) {                                         \
            v = v + (qa[j] - v) * K;                                          \
            mx = fmaxf(mx, v);                                                \
        }                                                                     \
        v = uB;                                                               \
        _Pragma("unroll")                                                     \
        for (int j = 0; j < 4; ++j) {                                         \
            v = v + (qb[j] - v) * K;                                          \
            mx = fmaxf(mx, v);                                                \
        }                                                                     \
        if (__builtin_expect(__ballot(mx >= 0.95f) != 0, 0)) {                \
            /* ~never: near-threshold row -> exact reference re-scan */       \
            const float* xr = x + base;                                       \
            unsigned m = 0;                                                   \
            float vv = 0.0f;                                                  \
            for (int t = 0; t < T_LEN; ++t) {                                 \
                const float xt = xr[t];       /* wave-uniform broadcast */    \
                vv = vv + (xt - vv) * K;                                      \
                if (vv >= 1.0f) {                                             \
                    vv = 0.0f;                                                \
                    const int q = t >> 2;                                     \
                    if (q == lane)      m |= 1u << (t & 3);                   \
                    if (q == lane + 64) m |= 1u << ((t & 3) + 4);             \
                }                                                             \
            }                                                                 \
            float* oA = out + base + (size_t)lane * 4;                        \
            _Pragma("unroll")                                                 \
            for (int j = 0; j < 4; ++j)                                       \
                if ((m >> j) & 1u) oA[j] = 1.0f;                              \
            _Pragma("unroll")                                                 \
            for (int j = 0; j < 4; ++j)                                       \
                if ((m >> (j + 4)) & 1u) oA[256 + j] = 1.0f;                  \
        }                                                                     \
    }

    for (int rr = 0; rr < RPW; rr += 2) {
        STEP(rr,     A0,  B0)
        STEP(rr + 1, A1v, B1v)
    }
#undef STEP
}

extern "C" void kernel_launch(void* const* d_in, const int* in_sizes, int n_in,
                              void* d_out, int out_size, void* d_ws, size_t ws_size,
                              hipStream_t stream) {
    const float* x = (const float*)d_in[0];
    float* out = (float*)d_out;

    // 1. pure write stream: zero the output
    zfill_kernel<<<dim3(2048), dim3(256), 0, stream>>>((f4*)out, out_size / 4);

    // 2. pure read stream: scan + (rare) exact spike scatter
    const int rows = in_sizes[0] / T_LEN;          // B*F = 131072
    const int grid = rows / (RPW * WPB);           // 1024 blocks
    lif_scan_kernel<<<dim3(grid), dim3(256), 0, stream>>>(x, out);
}

// Round 8
// 426.912 us; speedup vs baseline: 1.0095x; 1.0095x over previous
//
#include <hip/hip_runtime.h>

// LIF neuron forward scan, x: [B=64, F=2048, T=512] f32 (scan over contiguous T).
//   v = v + (x_t - v) * (DT/TAU);  s = (v >= 1); v *= (1 - s)
//
// Two kernels (output is statistically all-zero: threshold = 6.2 sigma of the
// membrane EMA; absmax=0.0 confirmed rounds 1-7):
//   1. zfill    : pure-write nontemporal zero-fill of d_out (~42 us floor).
//   2. lif_scan : pure-read wave-parallel affine scan, r7-validated math:
//        dense f4 loads (lane l owns t[4l..4l+4) of each 256-elem half-row),
//        per-lane 4-step fold -> 6-step shfl_up Hillis-Steele scan with
//        compile-time multipliers alpha^(4*2^s), half-to-half carry folded
//        into lane 0, exact in-lane pass-2 recurrence tracking max(v).
//        ballot(max >= 0.95)==0 (margin >> 1e-5 scan rounding) -> row is
//        provably spike-free -> write nothing. Else (~never) exact serial
//        reference re-scan decides and scatters 1.0f (rows uniquely owned).
//      NEW vs r7: 8 waves/SIMD (RPW=16, 2048 blocks, launch_bounds(256,8),
//      32 data VGPRs) and 4-ROW-DEEP prefetch (8 KB in flight per wave,
//      use-distance ~780 cy ~ HBM latency) -> read pipe never drains.

typedef float f4 __attribute__((ext_vector_type(4)));

#define T_LEN 512
#define RPW 16              // rows per wave
#define WPB 4               // waves per block

__global__ __launch_bounds__(256)
void zfill_kernel(f4* __restrict__ out, int n4) {
    const f4 z = {0.f, 0.f, 0.f, 0.f};
    int i = blockIdx.x * 256 + threadIdx.x;
    const int stride = gridDim.x * 256;
    for (; i < n4; i += stride)
        __builtin_nontemporal_store(z, out + i);
}

__global__ __launch_bounds__(256, 8)
void lif_scan_kernel(const float* __restrict__ x, float* __restrict__ out) {
    constexpr float  K   = 1.0f / 20.0f;
    constexpr double Kd  = (double)(1.0f / 20.0f);
    constexpr double A1d = 1.0 - Kd;
    constexpr double A2d = A1d * A1d;
    constexpr double A4d = A2d * A2d;        // per-lane segment (4 steps)
    constexpr double A8d = A4d * A4d;
    constexpr double A16d = A8d * A8d;
    constexpr double A32d = A16d * A16d;
    constexpr double A64d = A32d * A32d;
    constexpr double A128d = A64d * A64d;
    constexpr float C4[6] = {(float)A4d,  (float)A8d,  (float)A16d,
                             (float)A32d, (float)A64d, (float)A128d};
    constexpr float A4f = (float)A4d;

    const int lane = threadIdx.x & 63;
    const int wid  = blockIdx.x * WPB + (threadIdx.x >> 6);
    const size_t row0 = (size_t)wid * RPW;
    const float* px = x + row0 * T_LEN + lane * 4;   // lane base, row 0

    // 4-row-deep pipeline: rows RR..RR+3 in flight (8 f4 = 32 VGPRs data)
    f4 A0, B0, A1, B1, A2, B2, A3, B3;
    A0 = __builtin_nontemporal_load((const f4*)(px + 0 * T_LEN));
    B0 = __builtin_nontemporal_load((const f4*)(px + 0 * T_LEN + 256));
    A1 = __builtin_nontemporal_load((const f4*)(px + 1 * T_LEN));
    B1 = __builtin_nontemporal_load((const f4*)(px + 1 * T_LEN + 256));
    A2 = __builtin_nontemporal_load((const f4*)(px + 2 * T_LEN));
    B2 = __builtin_nontemporal_load((const f4*)(px + 2 * T_LEN + 256));
    A3 = __builtin_nontemporal_load((const f4*)(px + 3 * T_LEN));
    B3 = __builtin_nontemporal_load((const f4*)(px + 3 * T_LEN + 256));

#define STEP(RR, AV, BV)                                                      \
    {                                                                         \
        /* fold + scan, half A (t < 256) */                                   \
        float bA = 0.0f;                                                      \
        _Pragma("unroll")                                                     \
        for (int j = 0; j < 4; ++j) bA = bA + (AV[j] - bA) * K;               \
        _Pragma("unroll")                                                     \
        for (int s = 0; s < 6; ++s) {                                         \
            const float o = __shfl_up(bA, 1 << s);                            \
            const float f = fmaf(o, C4[s], bA);                               \
            bA = (lane >= (1 << s)) ? f : bA;                                 \
        }                                                                     \
        const float carry = __shfl(bA, 63);     /* v after t[0,256) */        \
        float uA = __shfl_up(bA, 1);                                          \
        uA = (lane == 0) ? 0.0f : uA;                                         \
        /* fold + scan, half B (carry folded into lane 0's segment) */        \
        float bB = 0.0f;                                                      \
        _Pragma("unroll")                                                     \
        for (int j = 0; j < 4; ++j) bB = bB + (BV[j] - bB) * K;               \
        bB = (lane == 0) ? fmaf(carry, A4f, bB) : bB;                         \
        _Pragma("unroll")                                                     \
        for (int s = 0; s < 6; ++s) {                                         \
            const float o = __shfl_up(bB, 1 << s);                            \
            const float f = fmaf(o, C4[s], bB);                               \
            bB = (lane >= (1 << s)) ? f : bB;                                 \
        }                                                                     \
        float uB = __shfl_up(bB, 1);                                          \
        uB = (lane == 0) ? carry : uB;                                        \
        /* pass 2: exact in-lane recurrence from entry potentials */          \
        float v = uA, mx = -1.0f;                                             \
        _Pragma("unroll")                                                     \
        for (int j = 0; j < 4; ++j) {                                         \
            v = v + (AV[j] - v) * K;                                          \
            mx = fmaxf(mx, v);                                                \
        }                                                                     \
        v = uB;                                                               \
        _Pragma("unroll")                                                     \
        for (int j = 0; j < 4; ++j) {                                         \
            v = v + (BV[j] - v) * K;                                          \
            mx = fmaxf(mx, v);                                                \
        }                                                                     \
        const unsigned long long hot = __ballot(mx >= 0.95f);                 \
        /* buffers dead -> prefetch row RR+4 (use-distance ~4 STEPs) */       \
        if ((RR) + 4 < RPW) {                                                 \
            AV = __builtin_nontemporal_load(                                  \
                (const f4*)(px + ((RR) + 4) * T_LEN));                        \
            BV = __builtin_nontemporal_load(                                  \
                (const f4*)(px + ((RR) + 4) * T_LEN + 256));                  \
        }                                                                     \
        if (__builtin_expect(hot != 0, 0)) {                                  \
            /* ~never: near-threshold row -> exact reference re-scan */       \
            const size_t base = (row0 + (RR)) * (size_t)T_LEN;                \
            const float* xr = x + base;                                       \
            unsigned m = 0;                                                   \
            float vv = 0.0f;                                                  \
            for (int t = 0; t < T_LEN; ++t) {                                 \
                const float xt = xr[t];                                       \
                vv = vv + (xt - vv) * K;                                      \
                if (vv >= 1.0f) {                                             \
                    vv = 0.0f;                                                \
                    const int q = t >> 2;                                     \
                    if (q == lane)      m |= 1u << (t & 3);                   \
                    if (q == lane + 64) m |= 1u << ((t & 3) + 4);             \
                }                                                             \
            }                                                                 \
            float* oA = out + base + (size_t)lane * 4;                        \
            _Pragma("unroll")                                                 \
            for (int j = 0; j < 4; ++j)                                       \
                if ((m >> j) & 1u) oA[j] = 1.0f;                              \
            _Pragma("unroll")                                                 \
            for (int j = 0; j < 4; ++j)                                       \
                if ((m >> (j + 4)) & 1u) oA[256 + j] = 1.0f;                  \
        }                                                                     \
    }

    STEP(0,  A0, B0)  STEP(1,  A1, B1)  STEP(2,  A2, B2)  STEP(3,  A3, B3)
    STEP(4,  A0, B0)  STEP(5,  A1, B1)  STEP(6,  A2, B2)  STEP(7,  A3, B3)
    STEP(8,  A0, B0)  STEP(9,  A1, B1)  STEP(10, A2, B2)  STEP(11, A3, B3)
    STEP(12, A0, B0)  STEP(13, A1, B1)  STEP(14, A2, B2)  STEP(15, A3, B3)
#undef STEP
}

extern "C" void kernel_launch(void* const* d_in, const int* in_sizes, int n_in,
                              void* d_out, int out_size, void* d_ws, size_t ws_size,
                              hipStream_t stream) {
    const float* x = (const float*)d_in[0];
    float* out = (float*)d_out;

    // 1. pure write stream: zero the output
    zfill_kernel<<<dim3(2048), dim3(256), 0, stream>>>((f4*)out, out_size / 4);

    // 2. pure read stream: scan + (rare) exact spike scatter
    const int rows = in_sizes[0] / T_LEN;          // B*F = 131072
    const int grid = rows / (RPW * WPB);           // 2048 blocks, 8192 waves
    lif_scan_kernel<<<dim3(grid), dim3(256), 0, stream>>>(x, out);
}